// Round 1
// 122.075 us; speedup vs baseline: 1.1059x; 1.1059x over previous
//
#include <hip/hip_runtime.h>
#include <hip/hip_bf16.h>
#include <cstddef>
#include <cstdint>

#define B_ 8
#define H_ 8
#define N_ 512
#define K_ 16
#define NN_ (N_*N_)

static constexpr float ALPHA_C = 0.001f;

typedef float f32x4 __attribute__((ext_vector_type(4)));

#define LDSTRIDE 20   // floats per LDS row: 16 + 4 pad, keeps 16B alignment

// -------------------------------------------------------------------------
// Strip matmul helpers. One wave owns one 16x16 matrix:
//   lane -> row r = lane>>2, col strip c0 = 4*(lane&3).
// B operand lives in LDS (row stride LDSTRIDE); per k the b128 read hits
// only 4 distinct addresses (16-way broadcast -> conflict-free & cheap).
// A operand is a register-cached full row (16 floats).
// -------------------------------------------------------------------------
__device__ __forceinline__ void mm_rowB(const float* a, const float* Bbuf,
                                        int c0, f32x4& acc)
{
    #pragma unroll
    for (int k = 0; k < 16; ++k) {
        const f32x4 bk = *(const f32x4*)&Bbuf[k * LDSTRIDE + c0];
        acc.x = fmaf(a[k], bk.x, acc.x);
        acc.y = fmaf(a[k], bk.y, acc.y);
        acc.z = fmaf(a[k], bk.z, acc.z);
        acc.w = fmaf(a[k], bk.w, acc.w);
    }
}

__device__ __forceinline__ void read_row(const float* buf, int r, float* a)
{
    #pragma unroll
    for (int i = 0; i < 4; ++i) {
        const f32x4 t = *(const f32x4*)&buf[r * LDSTRIDE + 4 * i];
        a[4*i]   = t.x; a[4*i+1] = t.y; a[4*i+2] = t.z; a[4*i+3] = t.w;
    }
}

__device__ __forceinline__ void write_strip(float* buf, int r, int c0, f32x4 s)
{
    *(f32x4*)&buf[r * LDSTRIDE + c0] = s;
}

// -------------------------------------------------------------------------
// Kernel 1: per (b,n): A = sum_g phi[g]*G_g (skew), Om = expm(A) via
// scaling-and-squaring + degree-12 Taylor in Paterson-Stockmeyer form
// (5 matmuls + s squarings; theta<=2 -> remainder ~1.3e-6, s=0 typical).
// One WAVE per matrix, no barriers. Emits Om, v = Om^T mu, q = 0.5||v||^2.
// -------------------------------------------------------------------------
__global__ __launch_bounds__(256) void expm_kernel(
    const float* __restrict__ mu, const float* __restrict__ phi,
    const float* __restrict__ gen, float* __restrict__ Om,
    float* __restrict__ v, float* __restrict__ q)
{
    __shared__ float lds[4][2][16 * LDSTRIDE];

    const int tid  = threadIdx.x;
    const int w    = tid >> 6, lane = tid & 63;
    const int r    = lane >> 2, c0 = (lane & 3) << 2;
    const int bn   = (blockIdx.x << 2) | w;

    float* U0 = lds[w][0];
    float* U1 = lds[w][1];

    // A strip = sum_g phi_g * G_g
    const float p0 = phi[bn*3+0], p1 = phi[bn*3+1], p2 = phi[bn*3+2];
    const int gidx = r * 16 + c0;
    const f32x4 g0 = *(const f32x4*)&gen[gidx];
    const f32x4 g1 = *(const f32x4*)&gen[256 + gidx];
    const f32x4 g2 = *(const f32x4*)&gen[512 + gidx];
    f32x4 As;
    As.x = p0*g0.x + p1*g1.x + p2*g2.x;
    As.y = p0*g0.y + p1*g1.y + p2*g2.y;
    As.z = p0*g0.z + p1*g1.z + p2*g2.z;
    As.w = p0*g0.w + p1*g1.w + p2*g2.w;

    // Frobenius norm -> scaling exponent (wave-uniform)
    float t = As.x*As.x + As.y*As.y + As.z*As.z + As.w*As.w;
    #pragma unroll
    for (int m = 1; m <= 32; m <<= 1) t += __shfl_xor(t, m, 64);
    float theta = sqrtf(t);
    int s = 0;
    while (theta > 2.0f && s < 30) { theta *= 0.5f; ++s; }
    const float sc = exp2f((float)(-s));
    const f32x4 Xs = As * sc;

    // X into U0; cache X row
    write_strip(U0, r, c0, Xs);
    float xrow[16];
    read_row(U0, r, xrow);

    // A2 = X*X
    f32x4 a2s = {0.f, 0.f, 0.f, 0.f};
    mm_rowB(xrow, U0, c0, a2s);
    write_strip(U1, r, c0, a2s);

    // A3 = X*A2 (strip only; never needed as a matmul operand)
    f32x4 a3s = {0.f, 0.f, 0.f, 0.f};
    mm_rowB(xrow, U1, c0, a3s);

    // A4 = A2*A2
    float a2row[16];
    read_row(U1, r, a2row);
    f32x4 a4s = {0.f, 0.f, 0.f, 0.f};
    mm_rowB(a2row, U1, c0, a4s);
    write_strip(U0, r, c0, a4s);       // U0 (X) dead as matmul operand now
    float a4row[16];
    read_row(U0, r, a4row);

    // Degree-3 coefficient blocks (all register strips)
    f32x4 di = {0.f, 0.f, 0.f, 0.f};
    if (r >= c0 && r < c0 + 4) ((float*)&di)[r - c0] = 1.0f;

    const f32x4 C0 = di + Xs + a2s * 0.5f + a3s * (1.0f/6.0f);
    const f32x4 C1 = di * (1.0f/24.0f) + Xs * (1.0f/120.0f)
                   + a2s * (1.0f/720.0f) + a3s * (1.0f/5040.0f);
    const f32x4 Q2 = di * (1.0f/40320.0f) + Xs * (1.0f/362880.0f)
                   + a2s * (1.0f/3628800.0f) + a3s * (1.0f/39916800.0f)
                   + a4s * (1.0f/479001600.0f);

    // T1 = C1 + A4*Q2
    write_strip(U1, r, c0, Q2);
    f32x4 T1 = C1;
    mm_rowB(a4row, U1, c0, T1);

    // P = C0 + A4*T1
    write_strip(U1, r, c0, T1);
    f32x4 P = C0;
    mm_rowB(a4row, U1, c0, P);

    // s squarings (s wave-uniform; no barriers -> divergence-safe)
    for (int it = 0; it < s; ++it) {
        write_strip(U1, r, c0, P);
        float prow[16];
        read_row(U1, r, prow);
        f32x4 Pn = {0.f, 0.f, 0.f, 0.f};
        mm_rowB(prow, U1, c0, Pn);
        P = Pn;
    }

    // store Om row-major (element [r][c] at r*16+c), coalesced b128
    *(f32x4*)&Om[(size_t)bn * 256 + r * 16 + c0] = P;

    // v[c] = sum_r Om[r][c] * mu[r]; reduce over r (xor masks 4..32)
    const float mur = mu[bn * 16 + r];
    f32x4 vc = P * mur;
    #pragma unroll
    for (int m = 4; m <= 32; m <<= 1) {
        vc.x += __shfl_xor(vc.x, m, 64);
        vc.y += __shfl_xor(vc.y, m, 64);
        vc.z += __shfl_xor(vc.z, m, 64);
        vc.w += __shfl_xor(vc.w, m, 64);
    }
    if (r == 0) *(f32x4*)&v[bn * 16 + c0] = vc;

    float qp = vc.x*vc.x + vc.y*vc.y + vc.z*vc.z + vc.w*vc.w;
    qp += __shfl_xor(qp, 1, 64);
    qp += __shfl_xor(qp, 2, 64);
    if (lane == 0) q[bn] = 0.5f * qp;
}

// -------------------------------------------------------------------------
// Kernel 2: memory-bound pass over beta. One wave per (b,i); 4 i per block
// sharing a transposed LDS copy of v[b].
//
// v3 memory schedule: (1) v-staging loads -> regs, (2) ALL 16 beta streams
// (8 h x 2 j-halves) issued as one nontemporal burst, (3) LDS scatter of v
// (counted vmcnt: waits only on the staging loads, beta stays in flight),
// (4) barrier, (5) h-mean consumed from registers. One HBM-latency exposure
// per wave, hidden behind the scatter+barrier, instead of two exposed
// ~900-cycle stalls in the middle of the compute loop.
// -------------------------------------------------------------------------
__global__ __launch_bounds__(256, 4) void grad_kernel(
    const float* __restrict__ mu, const float* __restrict__ beta,
    const float* __restrict__ mu_prior, const float* __restrict__ lrp,
    const float* __restrict__ Om, const float* __restrict__ v,
    const float* __restrict__ q, float* __restrict__ out)
{
    __shared__ float v_t[16 * 516];      // 16 rows x 129 float4 (pad 1 f4)
    __shared__ f32x4 q4[128];

    const int blk = blockIdx.x;          // 0..1023
    const int b   = blk >> 7;
    const int i0  = (blk & 127) << 2;
    const int tid = threadIdx.x;
    const int wid = tid >> 6, lane = tid & 63;
    const int i   = i0 + wid;

    // ---- 1. issue v[b] staging loads into registers (oldest in vmcnt) ----
    const float* vb = v + (size_t)b * N_ * K_;
    f32x4 tq[8];
    #pragma unroll
    for (int s = 0; s < 8; ++s)
        tq[s] = *(const f32x4*)&vb[(tid + 256 * s) << 2];

    f32x4 qreg = {0.f, 0.f, 0.f, 0.f};
    const f32x4* qb4 = (const f32x4*)(q + (size_t)b * N_);
    if (tid < 128) qreg = qb4[tid];

    // ---- 2. issue all 16 beta streams (nontemporal burst, 16B/lane) ----
    const size_t betaBase = (((size_t)b * H_) * N_ + i) * N_;
    const float* bp = beta + betaBase + (lane << 2);
    f32x4 bt[16];
    #pragma unroll
    for (int h = 0; h < H_; ++h) {
        bt[2*h+0] = __builtin_nontemporal_load((const f32x4*)(bp + (size_t)h * NN_));
        bt[2*h+1] = __builtin_nontemporal_load((const f32x4*)(bp + (size_t)h * NN_ + 256));
    }

    // ---- 3. LDS scatter of staged v (transposed); beta still in flight ----
    #pragma unroll
    for (int s = 0; s < 8; ++s) {
        const int f4 = tid + 256 * s;
        const int j  = f4 >> 2;
        const int k0 = (f4 & 3) << 2;
        v_t[(k0+0) * 516 + j] = tq[s].x;
        v_t[(k0+1) * 516 + j] = tq[s].y;
        v_t[(k0+2) * 516 + j] = tq[s].z;
        v_t[(k0+3) * 516 + j] = tq[s].w;
    }
    if (tid < 128) q4[tid] = qreg;
    __syncthreads();

    // ---- 4. h-mean for both j-halves, from registers ----
    f32x4 rv0 = bt[0], rv1 = bt[1];
    #pragma unroll
    for (int h = 1; h < H_; ++h) { rv0 += bt[2*h]; rv1 += bt[2*h+1]; }
    rv0 *= 0.125f; rv1 *= 0.125f;

    float vi[16];
    #pragma unroll
    for (int k = 0; k < 16; ++k) vi[k] = v_t[k * 516 + i];   // broadcast
    const float qi = ((const float*)q4)[i];

    float w1[16], w2[16];
    #pragma unroll
    for (int k = 0; k < 16; ++k) { w1[k] = 0.f; w2[k] = 0.f; }
    float sacc = 0.f, R = 0.f;

    #pragma unroll
    for (int p = 0; p < 2; ++p) {
        const int j0 = (lane << 2) | (p << 8);
        const float rx = p ? rv1.x : rv0.x;
        const float ry = p ? rv1.y : rv0.y;
        const float rz = p ? rv1.z : rv0.z;
        const float rw = p ? rv1.w : rv0.w;

        float d0 = 0.f, d1 = 0.f, d2 = 0.f, d3 = 0.f;
        #pragma unroll
        for (int k = 0; k < 16; ++k) {
            const f32x4 vj = *(const f32x4*)&v_t[k * 516 + j0];
            d0 = fmaf(vi[k], vj.x, d0);
            d1 = fmaf(vi[k], vj.y, d1);
            d2 = fmaf(vi[k], vj.z, d2);
            d3 = fmaf(vi[k], vj.w, d3);
        }
        const f32x4 qj = q4[lane | (p << 6)];
        const float rkl0 = rx * (qi + qj.x - d0);
        const float rkl1 = ry * (qi + qj.y - d1);
        const float rkl2 = rz * (qi + qj.z - d2);
        const float rkl3 = rw * (qi + qj.w - d3);
        sacc += (rkl0 + rkl1) + (rkl2 + rkl3);
        R    += (rx + ry) + (rz + rw);

        #pragma unroll
        for (int k = 0; k < 16; ++k) {
            const f32x4 vj = *(const f32x4*)&v_t[k * 516 + j0];
            float a1 = fmaf(rx, vj.x, w1[k]);
            a1 = fmaf(ry, vj.y, a1);
            a1 = fmaf(rz, vj.z, a1);
            w1[k] = fmaf(rw, vj.w, a1);
            float a2 = fmaf(rkl0, vj.x, w2[k]);
            a2 = fmaf(rkl1, vj.y, a2);
            a2 = fmaf(rkl2, vj.z, a2);
            w2[k] = fmaf(rkl3, vj.w, a2);
        }
    }

    // ---- stage A: full butterfly for the two scalars only ----
    #pragma unroll
    for (int off = 32; off > 0; off >>= 1) {
        sacc += __shfl_xor(sacc, off, 64);
        R    += __shfl_xor(R,    off, 64);
    }
    const float oms  = 1.0f - sacc;
    const float coef = oms * R + sacc;

    // ---- stage B: fold wc = (1-s)*w1 + w2 (oms is wave-uniform) ----
    float wc[16];
    #pragma unroll
    for (int k = 0; k < 16; ++k) wc[k] = fmaf(oms, w1[k], w2[k]);

    // ---- stage C: halving exchange; lane ends with sum of wc[c],
    //      c = (lane>>2)&15 ----
    {
        #pragma unroll
        for (int k = 0; k < 8; ++k) {             // mask 32, keep 8
            const bool up = (lane & 32) != 0;
            const float send = up ? wc[k] : wc[k + 8];
            const float recv = __shfl_xor(send, 32, 64);
            wc[k] = (up ? wc[k + 8] : wc[k]) + recv;
        }
        #pragma unroll
        for (int k = 0; k < 4; ++k) {             // mask 16, keep 4
            const bool up = (lane & 16) != 0;
            const float send = up ? wc[k] : wc[k + 4];
            const float recv = __shfl_xor(send, 16, 64);
            wc[k] = (up ? wc[k + 4] : wc[k]) + recv;
        }
        #pragma unroll
        for (int k = 0; k < 2; ++k) {             // mask 8, keep 2
            const bool up = (lane & 8) != 0;
            const float send = up ? wc[k] : wc[k + 2];
            const float recv = __shfl_xor(send, 8, 64);
            wc[k] = (up ? wc[k + 2] : wc[k]) + recv;
        }
        {                                          // mask 4, keep 1
            const bool up = (lane & 4) != 0;
            const float send = up ? wc[0] : wc[1];
            const float recv = __shfl_xor(send, 4, 64);
            wc[0] = (up ? wc[1] : wc[0]) + recv;
        }
        wc[0] += __shfl_xor(wc[0], 2, 64);
        wc[0] += __shfl_xor(wc[0], 1, 64);
    }

    // ---- stage D: distributed rotation. lane handles component c and
    //      4 rows 4t..4t+3 (t = lane&3) of Om_i; 5-shuffle c-reduction ----
    const int cmine = (lane >> 2) & 15;
    const float gv = coef * v_t[cmine * 516 + i] - wc[0];

    const size_t rowi = (size_t)b * N_ + i;
    const float* omb = Om + rowi * 256;
    const int tqi = lane & 3;
    float pr[4];
    #pragma unroll
    for (int rr = 0; rr < 4; ++rr)
        pr[rr] = omb[(4 * tqi + rr) * 16 + cmine] * gv;

    #pragma unroll
    for (int k = 0; k < 2; ++k) {                 // mask 4, keep 2
        const bool up = (lane & 4) != 0;
        const float send = up ? pr[k] : pr[k + 2];
        const float recv = __shfl_xor(send, 4, 64);
        pr[k] = (up ? pr[k + 2] : pr[k]) + recv;
    }
    {                                              // mask 8, keep 1
        const bool up = (lane & 8) != 0;
        const float send = up ? pr[0] : pr[1];
        const float recv = __shfl_xor(send, 8, 64);
        pr[0] = (up ? pr[1] : pr[0]) + recv;
    }
    pr[0] += __shfl_xor(pr[0], 16, 64);
    pr[0] += __shfl_xor(pr[0], 32, 64);
    // lane now holds S_row, row = 4t + 2*bit2 + bit3

    if (lane < 16) {
        const int row = 4 * tqi + 2 * ((lane >> 2) & 1) + ((lane >> 3) & 1);
        const float lr = lrp[0];
        const size_t oi = rowi * 16 + row;
        const float m0 = mu[oi], mp = mu_prior[oi];
        out[oi] = m0 - lr * (ALPHA_C * (m0 - mp) + pr[0]);
    }
}

// -------------------------------------------------------------------------
extern "C" void kernel_launch(void* const* d_in, const int* in_sizes, int n_in,
                              void* d_out, int out_size, void* d_ws, size_t ws_size,
                              hipStream_t stream)
{
    const float* mu   = (const float*)d_in[0];
    const float* beta = (const float*)d_in[1];
    const float* mup  = (const float*)d_in[2];
    const float* phi  = (const float*)d_in[3];
    const float* gen  = (const float*)d_in[4];
    const float* lr   = (const float*)d_in[5];
    float* out = (float*)d_out;

    float* Om = (float*)d_ws;                       // 4096*256 floats = 4 MB
    float* v  = Om + (size_t)4096 * 256;            // 4096*16
    float* q  = v  + (size_t)4096 * 16;             // 4096

    expm_kernel<<<B_ * N_ / 4, 256, 0, stream>>>(mu, phi, gen, Om, v, q);
    grad_kernel<<<B_ * (N_ / 4), 256, 0, stream>>>(mu, beta, mup, lr, Om, v, q, out);
}